// Round 1
// 363.018 us; speedup vs baseline: 1.0937x; 1.0937x over previous
//
#include <hip/hip_runtime.h>
#include <stdint.h>

// ---------------------------------------------------------------------------
// OptitationLayer: sliding-window attention (W=9) with projections.
//   S=32768, D=1024, R=256. Inputs/outputs FLOAT32; bf16 MFMA internally.
// Pipeline (5 kernels):
//   prep_w : coalesced LDS-tile transposes f32->bf16: Wt[768][1024], Wot[1024][256]
//   cvt_x  : x f32 -> bf16 (BW-bound pass; unlocks global_load_lds staging in GEMM1)
//   gemm_bt: QKV[S][768] bf16 = x_bf16 @ W + bias   (async bf16 staging path)
//   attn   : QKV[i][0:256] <- softmax-window ctx (in-place, 4 queries/wave)
//   gemm_bt: out[S][1024] f32 = ctx @ Wo + bo
// XCD swizzle: dispatch i -> XCD i%8 (round robin). Map so all n-tiles of an
// m-row land on ONE xcd => A tile fetched by a single L2 (was 3x over-fetch).
// ---------------------------------------------------------------------------

typedef __attribute__((ext_vector_type(8))) short short8;   // 8 x bf16 frag
typedef __attribute__((ext_vector_type(4))) float floatx4;  // MFMA acc

typedef __attribute__((address_space(1))) const void global_cv;
typedef __attribute__((address_space(3))) void lds_v;

__device__ __forceinline__ float b2f(unsigned short u) {
  union { float f; uint32_t i; } v; v.i = ((uint32_t)u) << 16; return v.f;
}
__device__ __forceinline__ unsigned short f2b(float f) {
  union { float f; uint32_t i; } v; v.f = f;
  uint32_t x = v.i;
  return (unsigned short)((x + 0x7FFFu + ((x >> 16) & 1u)) >> 16);
}
// pack two f32 -> two bf16 (round half-up; 3 VALU ops)
__device__ __forceinline__ uint32_t pack2bf(float a, float b) {
  uint32_t ua = (__float_as_uint(a) + 0x8000u) >> 16;
  uint32_t ub = (__float_as_uint(b) + 0x8000u) & 0xFFFF0000u;
  return ua | ub;
}

// async 16B global->LDS; lane i lands at lds_base + i*16 (wave-uniform base)
__device__ __forceinline__ void async16(const unsigned short* g, unsigned short* s) {
  __builtin_amdgcn_global_load_lds((global_cv*)g, (lds_v*)s, 16, 0, 0);
}

__device__ __forceinline__ void storeC(unsigned short* C, size_t idx, float v) {
  C[idx] = f2b(v);
}
__device__ __forceinline__ void storeC(float* C, size_t idx, float v) {
  C[idx] = v;
}

// x (f32, n8*8 elems) -> xb (bf16). Pure-BW grid-stride pass: 32B read, 16B
// write per lane-iter, fully coalesced.
__global__ __launch_bounds__(256) void cvt_x(
    const float* __restrict__ x, unsigned short* __restrict__ xb, int n8)
{
  const int stride = gridDim.x * blockDim.x;
  for (int i = blockIdx.x * blockDim.x + threadIdx.x; i < n8; i += stride) {
    const float4 u = ((const float4*)x)[2 * i];
    const float4 v = ((const float4*)x)[2 * i + 1];
    uint4 pk;
    pk.x = pack2bf(u.x, u.y); pk.y = pack2bf(u.z, u.w);
    pk.z = pack2bf(v.x, v.y); pk.w = pack2bf(v.z, v.w);
    ((uint4*)xb)[i] = pk;
  }
}

// C[m][n] = sum_k A[m][k]*Bt[n][k] + bias[n].
// AF32: A is f32, converted to bf16 during LDS staging. Else A bf16 via async.
// Grid: 1-D, (M/128)*NT blocks; NT = N/128 (compile-time).
template <typename CT, bool AF32, int NT>
__global__ __launch_bounds__(256) void gemm_bt(
    const void* __restrict__ Aptr,
    const unsigned short* __restrict__ Bt,   // [N x ldb] bf16
    const float* __restrict__ bias,          // [N] f32
    CT* __restrict__ C,                      // [M x ldc]
    int K, int lda, int ldb, int ldc)
{
  __shared__ __align__(16) unsigned short sA[128 * 64];  // 16 KB
  __shared__ __align__(16) unsigned short sB[128 * 64];  // 16 KB

  const int tid = threadIdx.x;
  const int w   = tid >> 6;   // wave 0..3
  const int l   = tid & 63;   // lane
  const int l15 = l & 15;
  const int q   = l >> 4;     // quad 0..3

  // XCD-aware remap: dispatch -> (m,n) so one XCD owns all n-tiles of an m-row
  const int bt  = blockIdx.x;
  const int xcd = bt & 7;
  const int j_  = bt >> 3;
  const int n0  = (j_ % NT) * 128;
  const int m0  = ((j_ / NT) * 8 + xcd) * 128;

  const int wm  = (w >> 1) * 64;      // wave's 64x64 quadrant
  const int wn  = (w & 1) * 64;

  floatx4 acc[4][4];
  #pragma unroll
  for (int i = 0; i < 4; ++i)
    #pragma unroll
    for (int j = 0; j < 4; ++j)
      #pragma unroll
      for (int t = 0; t < 4; ++t) acc[i][j][t] = 0.f;

  const int srow = l >> 3;  // staging row within 8-row group
  const int sch  = l & 7;   // physical 16B chunk within the row
  const int arow = tid >> 1;       // AF32: tile row 0..127
  const int acb  = (tid & 1) * 4;  // AF32: chunk base 0 or 4

  for (int k0 = 0; k0 < K; k0 += 64) {
    // ---- B staging: async 16B, XOR-swizzled chunks
    #pragma unroll
    for (int jj = 0; jj < 4; ++jj) {
      const int rr = (jj * 4 + w) * 8 + srow;
      const int kc = sch ^ (rr & 7);
      async16(Bt + (size_t)(n0 + rr) * ldb + (k0 + kc * 8),
              sB + (jj * 4 + w) * 512);
    }
    // ---- A staging
    if constexpr (AF32) {
      const float* A = (const float*)Aptr;
      const float* src = A + (size_t)(m0 + arow) * lda + k0 + acb * 8;
      #pragma unroll
      for (int c = 0; c < 4; ++c) {
        const float4 u = *(const float4*)(src + c * 8);
        const float4 v = *(const float4*)(src + c * 8 + 4);
        uint4 pk;
        pk.x = pack2bf(u.x, u.y); pk.y = pack2bf(u.z, u.w);
        pk.z = pack2bf(v.x, v.y); pk.w = pack2bf(v.z, v.w);
        const int pch = (acb + c) ^ (arow & 7);   // same swizzle as read side
        *(uint4*)(sA + arow * 64 + pch * 8) = pk;
      }
    } else {
      const unsigned short* A = (const unsigned short*)Aptr;
      #pragma unroll
      for (int jj = 0; jj < 4; ++jj) {
        const int rr = (jj * 4 + w) * 8 + srow;
        const int kc = sch ^ (rr & 7);
        async16(A + (size_t)(m0 + rr) * lda + (k0 + kc * 8),
                sA + (jj * 4 + w) * 512);
      }
    }
    __syncthreads();  // drains vmcnt + lgkmcnt -> LDS data visible

    #pragma unroll
    for (int kt = 0; kt < 2; ++kt) {
      short8 af[4], bf[4];
      #pragma unroll
      for (int mt = 0; mt < 4; ++mt) {
        const int row = wm + mt * 16 + l15;
        const int pc  = (kt * 4 + q) ^ (row & 7);
        af[mt] = *(const short8*)(sA + row * 64 + pc * 8);  // ds_read_b128
      }
      #pragma unroll
      for (int nt = 0; nt < 4; ++nt) {
        const int row = wn + nt * 16 + l15;
        const int pc  = (kt * 4 + q) ^ (row & 7);
        bf[nt] = *(const short8*)(sB + row * 64 + pc * 8);
      }
      #pragma unroll
      for (int mt = 0; mt < 4; ++mt)
        #pragma unroll
        for (int nt = 0; nt < 4; ++nt)
          acc[mt][nt] = __builtin_amdgcn_mfma_f32_16x16x32_bf16(
              af[mt], bf[nt], acc[mt][nt], 0, 0, 0);
    }
    __syncthreads();  // protect LDS before next staging pass
  }

  // ---- epilogue: C/D layout col=lane&15, row=quad*4+reg
  #pragma unroll
  for (int nt = 0; nt < 4; ++nt) {
    const int col = n0 + wn + nt * 16 + l15;
    const float bs = bias[col];
    #pragma unroll
    for (int mt = 0; mt < 4; ++mt) {
      const int rbase = m0 + wm + mt * 16 + q * 4;
      #pragma unroll
      for (int r = 0; r < 4; ++r)
        storeC(C, (size_t)(rbase + r) * ldc + col, acc[mt][nt][r] + bs);
    }
  }
}

// 4 queries per wave, 16 lanes per query (lane p owns dims p*16..p*16+15).
// QKV row: [Q(0..255) | K(256..511) | V(512..767)], bf16. ctx overwrites Q
// slot in place (each group reads only its own Q row, before its store).
__global__ __launch_bounds__(256) void attn_win(unsigned short* QKV)
{
  const int l   = threadIdx.x & 63;
  const int grp = l >> 4;
  const int p   = l & 15;
  const int i   = blockIdx.x * 16 + (threadIdx.x >> 6) * 4 + grp;

  unsigned short* qrow = QKV + (size_t)i * 768 + p * 16;
  float qf[16];
  {
    const short8 v0 = *(const short8*)(qrow);
    const short8 v1 = *(const short8*)(qrow + 8);
    #pragma unroll
    for (int t = 0; t < 8; ++t) {
      qf[t]     = b2f((unsigned short)v0[t]);
      qf[8 + t] = b2f((unsigned short)v1[t]);
    }
  }

  float sc[9];
  #pragma unroll
  for (int wd = 0; wd < 9; ++wd) {
    const int j = i - 8 + wd;
    if (j >= 0) {
      const unsigned short* krow = QKV + (size_t)j * 768 + 256 + p * 16;
      const short8 v0 = *(const short8*)(krow);
      const short8 v1 = *(const short8*)(krow + 8);
      float d = 0.f;
      #pragma unroll
      for (int t = 0; t < 8; ++t) {
        d += qf[t]     * b2f((unsigned short)v0[t]);
        d += qf[8 + t] * b2f((unsigned short)v1[t]);
      }
      // reduce across the 16-lane group (source lanes share the branch)
      d += __shfl_xor(d, 8, 64);
      d += __shfl_xor(d, 4, 64);
      d += __shfl_xor(d, 2, 64);
      d += __shfl_xor(d, 1, 64);
      sc[wd] = d * 0.0625f;  // 1/sqrt(256)
    } else {
      sc[wd] = -1e30f;  // finite sentinel
    }
  }

  float mx = sc[0];
  #pragma unroll
  for (int wd = 1; wd < 9; ++wd) mx = fmaxf(mx, sc[wd]);
  float e[9], s = 0.f;
  #pragma unroll
  for (int wd = 0; wd < 9; ++wd) { e[wd] = __expf(sc[wd] - mx); s += e[wd]; }
  const float inv = 1.0f / s;

  float acc[16];
  #pragma unroll
  for (int t = 0; t < 16; ++t) acc[t] = 0.f;
  #pragma unroll
  for (int wd = 0; wd < 9; ++wd) {
    const int j = i - 8 + wd;
    if (j >= 0) {
      const unsigned short* vrow = QKV + (size_t)j * 768 + 512 + p * 16;
      const short8 v0 = *(const short8*)(vrow);
      const short8 v1 = *(const short8*)(vrow + 8);
      #pragma unroll
      for (int t = 0; t < 8; ++t) {
        acc[t]     += e[wd] * b2f((unsigned short)v0[t]);
        acc[8 + t] += e[wd] * b2f((unsigned short)v1[t]);
      }
    }
  }
  short8 o0, o1;
  #pragma unroll
  for (int t = 0; t < 8; ++t) {
    o0[t] = (short)f2b(acc[t] * inv);
    o1[t] = (short)f2b(acc[8 + t] * inv);
  }
  *(short8*)(qrow)     = o0;   // overwrite Q slot
  *(short8*)(qrow + 8) = o1;
}

// Coalesced weight transposes via 32x32 LDS tiles (f32 -> bf16) + biases.
// Blocks 0..767: Wq/Wk/Wv -> Wt[768][1024]; 768..1023: Wo -> Wot[1024][256];
// block 1024: bias concat.
__global__ __launch_bounds__(256) void prep_w(
    const float* __restrict__ Wq, const float* __restrict__ Wk,
    const float* __restrict__ Wv, const float* __restrict__ Wo,
    const float* __restrict__ bq, const float* __restrict__ bk,
    const float* __restrict__ bv, const float* __restrict__ bo,
    unsigned short* __restrict__ Wt,   // [768][1024] bf16
    unsigned short* __restrict__ Wot,  // [1024][256] bf16
    float* __restrict__ bias1,         // [768] f32
    float* __restrict__ bias2)         // [1024] f32
{
  const int tt = blockIdx.x;
  if (tt < 1024) {
    __shared__ float tile[32][33];
    const float* src; unsigned short* dst; int N, Kd, k0, n0;
    if (tt < 768) {
      const int s = tt >> 8;          // 0:Wq 1:Wk 2:Wv
      const int r = tt & 255;
      src = (s == 0) ? Wq : (s == 1) ? Wk : Wv;
      N = 256; Kd = 1024;
      k0 = (r & 31) * 32;             // 32 k-tiles
      n0 = (r >> 5) * 32;             // 8 n-tiles
      dst = Wt + (size_t)s * 256 * 1024;
    } else {
      const int r = tt - 768;
      src = Wo; N = 1024; Kd = 256;
      k0 = (r & 7) * 32;              // 8 k-tiles
      n0 = (r >> 3) * 32;             // 32 n-tiles
      dst = Wot;
    }
    const int t  = threadIdx.x;
    const int rr = t >> 3;            // 0..31
    const int c4 = (t & 7) * 4;       // 0,4,..,28
    const float4 v = *(const float4*)(src + (size_t)(k0 + rr) * N + n0 + c4);
    tile[rr][c4 + 0] = v.x; tile[rr][c4 + 1] = v.y;
    tile[rr][c4 + 2] = v.z; tile[rr][c4 + 3] = v.w;
    __syncthreads();
    ushort4 o;
    o.x = f2b(tile[c4 + 0][rr]); o.y = f2b(tile[c4 + 1][rr]);
    o.z = f2b(tile[c4 + 2][rr]); o.w = f2b(tile[c4 + 3][rr]);
    *(ushort4*)(dst + (size_t)(n0 + rr) * Kd + k0 + c4) = o;
  } else {
    for (int c = threadIdx.x; c < 1792; c += 256) {
      if (c < 768)
        bias1[c] = (c < 256) ? bq[c] : (c < 512) ? bk[c - 256] : bv[c - 512];
      else
        bias2[c - 768] = bo[c - 768];
    }
  }
}

extern "C" void kernel_launch(void* const* d_in, const int* in_sizes, int n_in,
                              void* d_out, int out_size, void* d_ws, size_t ws_size,
                              hipStream_t stream) {
  const float* x  = (const float*)d_in[0];
  const float* Wq = (const float*)d_in[1];
  const float* Wk = (const float*)d_in[2];
  const float* Wv = (const float*)d_in[3];
  const float* Wo = (const float*)d_in[4];
  const float* bq = (const float*)d_in[5];
  const float* bk = (const float*)d_in[6];
  const float* bv = (const float*)d_in[7];
  const float* bo = (const float*)d_in[8];
  float* out = (float*)d_out;

  // workspace layout — 119.5 MB if it fits; else x_bf16 spills into d_out
  // (d_out = 134 MB, only consumed by the last GEMM => stream-ordered safe).
  unsigned short* ws    = (unsigned short*)d_ws;
  unsigned short* Wt    = ws;                        //   786432 bf16
  unsigned short* Wot   = Wt  + 786432;              //   262144 bf16
  float*          bias1 = (float*)(Wot + 262144);    //      768 f32
  float*          bias2 = bias1 + 768;               //     1024 f32
  unsigned short* QKV   = (unsigned short*)(bias2 + 1024);  // 25165824 bf16
  unsigned short* xb;                                // 33554432 bf16
  const size_t need = 119544832;                     // bytes incl. xb
  if (ws_size >= need) xb = QKV + 25165824;
  else                 xb = (unsigned short*)d_out;  // scratch until last GEMM

  prep_w<<<1025, 256, 0, stream>>>(Wq, Wk, Wv, Wo, bq, bk, bv, bo,
                                   Wt, Wot, bias1, bias2);

  // x f32 -> bf16 (unlocks global_load_lds staging in the QKV GEMM)
  cvt_x<<<2048, 256, 0, stream>>>(x, xb, 32768 * 1024 / 8);

  // QKV = x @ [Wq|Wk|Wv] + bias   (M=32768, N=768, K=1024; A bf16 async)
  gemm_bt<unsigned short, false, 6><<<1536, 256, 0, stream>>>(
      (const void*)xb, Wt, bias1, QKV, 1024, 1024, 1024, 768);

  // windowed attention: ctx overwrites the Q slot of QKV
  attn_win<<<2048, 256, 0, stream>>>(QKV);

  // out = ctx @ Wo + bo   (M=32768, N=1024, K=256; A = QKV with lda=768)
  gemm_bt<float, false, 8><<<2048, 256, 0, stream>>>(
      (const void*)QKV, Wot, bias2, out, 256, 768, 256, 1024);
}